// Round 2
// baseline (306.271 us; speedup 1.0000x reference)
//
#include <hip/hip_runtime.h>

typedef unsigned short u16;
typedef unsigned int u32;
typedef __attribute__((ext_vector_type(8))) short short8;
typedef __attribute__((ext_vector_type(4))) float f32x4;

__device__ __forceinline__ u16 f2bf(float f) {
  u32 u = __builtin_bit_cast(u32, f);
  u += 0x7fffu + ((u >> 16) & 1u);
  return (u16)(u >> 16);
}
__device__ __forceinline__ float bf2f(u16 h) {
  u32 u = ((u32)h) << 16;
  return __builtin_bit_cast(float, u);
}

__device__ __forceinline__ void async16(const void* g, void* l) {
  __builtin_amdgcn_global_load_lds(
      (const __attribute__((address_space(1))) u32*)g,
      (__attribute__((address_space(3))) u32*)l, 16, 0, 0);
}

// ---------------- weight transpose: in (K x N) f32 -> outT (N x K) bf16 ----
// scaleN: rows n < scaleN get * 0.125 (folds q-scale into w_qkv)
__global__ __launch_bounds__(256) void k_wt(const float* __restrict__ in,
                                            u16* __restrict__ outT,
                                            int K, int N, int scaleN) {
  const int bid = blockIdx.x;
  const int ntiles = N >> 5;
  const int nt = bid % ntiles, kt = bid / ntiles;
  const int n0 = nt << 5, k0 = kt << 5;
  __shared__ float tile[32][33];
  const int t = threadIdx.x;
#pragma unroll
  for (int i = 0; i < 4; ++i) {
    const int e = t + i * 256, r = e >> 5, c = e & 31;  // r: k, c: n
    tile[c][r] = in[(size_t)(k0 + r) * N + n0 + c];
  }
  __syncthreads();
#pragma unroll
  for (int i = 0; i < 4; ++i) {
    const int e = t + i * 256, r = e >> 5, c = e & 31;  // r: n, c: k
    float v = tile[r][c];
    if (n0 + r < scaleN) v *= 0.125f;
    outT[(size_t)(n0 + r) * K + k0 + c] = f2bf(v);
  }
}

// ---- x transpose: (b,c,f,h,w) f32 -> XT[(b,spatial)*16+f][c] bf16 (site-major)
__global__ __launch_bounds__(256) void k_xt(const float* __restrict__ x,
                                            u16* __restrict__ XT) {
  const int bid = blockIdx.x;
  const int plane = bid & 31;   // b*16 + f
  const int rest = bid >> 5;
  const int mt = rest & 31, ct = rest >> 5;
  const int bb = plane >> 4, f = plane & 15;
  const int m0 = mt << 5, c0 = ct << 5;
  __shared__ float tile[32][33];
  const int t = threadIdx.x;
#pragma unroll
  for (int i = 0; i < 4; ++i) {
    const int e = t + i * 256, r = e >> 5, c = e & 31;  // r: ch, c: m(spatial)
    tile[c][r] = x[((size_t)((bb * 512 + c0 + r) * 16 + f)) * 1024 + m0 + c];
  }
  __syncthreads();
#pragma unroll
  for (int i = 0; i < 4; ++i) {
    const int e = t + i * 256, r = e >> 5, c = e & 31;  // r: m, c: ch
    XT[((size_t)((bb * 1024 + m0 + r) * 16 + f)) * 512 + c0 + c] = f2bf(tile[r][c]);
  }
}

// ---------------- fused QKV GEMM + attention ------------------------------
// block = (M-tile of 128 rows = 8 sites x 16 f) x (one head: q|k|v 192 cols),
// K=512. k_proj-style async16-staged MFMA GEMM, then in-block VALU attention
// for the 8 sites (2 per wave). Staging LDS unioned with attention LDS.
struct A2St { u16 A[128][64]; u16 B[192][64]; };
struct A2At { u16 qkv[8][16][200]; float p[8][16][17]; };  // 200: 16B-aligned rows
union A2Sm { A2St st; A2At at; };

__global__ __launch_bounds__(256) void k_qkv_attn(const u16* __restrict__ XT,
                                                  const u16* __restrict__ WQ,
                                                  const float* __restrict__ pos_bias,
                                                  u16* __restrict__ AO) {
  const int tid = threadIdx.x;
  const int w = tid >> 6, lane = tid & 63;
  const int c15 = lane & 15, quad = lane >> 4;
  const int bid = blockIdx.x;          // 2048 blocks = 256 M-tiles x 8 heads
  const int hd = bid & 7, m0 = (bid >> 3) << 7;

  __shared__ A2Sm sm;

  const int lr = lane >> 3, lcb = lane & 7;

  f32x4 acc[3][8];
#pragma unroll
  for (int c = 0; c < 3; ++c)
#pragma unroll
    for (int mt = 0; mt < 8; ++mt) acc[c][mt] = f32x4{0.f, 0.f, 0.f, 0.f};

  for (int kk = 0; kk < 8; ++kk) {
    __syncthreads();
    const int kc = kk << 6;
    // A: 128 rows, wave w stages rows w*32..+32
#pragma unroll
    for (int t2 = 0; t2 < 4; ++t2) {
      const int r = w * 32 + t2 * 8 + lr;
      const int swcol = kc + ((lcb ^ (r & 7)) << 3);
      async16(XT + (size_t)(m0 + r) * 512 + swcol, &sm.st.A[w * 32 + t2 * 8][0]);
    }
    // B: 192 rows (q|k|v of head hd), wave w stages rows w*48..+48
#pragma unroll
    for (int t2 = 0; t2 < 6; ++t2) {
      const int j = w * 48 + t2 * 8 + lr;
      const int grow = (j >> 6) * 512 + hd * 64 + (j & 63);
      const int swcol = kc + ((lcb ^ (j & 7)) << 3);
      async16(WQ + (size_t)grow * 512 + swcol, &sm.st.B[w * 48 + t2 * 8][0]);
    }
    __syncthreads();
#pragma unroll
    for (int half = 0; half < 2; ++half) {
      short8 af[8], bt[3];
#pragma unroll
      for (int mt = 0; mt < 8; ++mt) {
        const int row = mt * 16 + c15;
        const int swz = (((half << 2) + quad) ^ (row & 7)) << 3;
        af[mt] = *(const short8*)&sm.st.A[row][swz];
      }
#pragma unroll
      for (int c = 0; c < 3; ++c) {
        const int row = c * 64 + w * 16 + c15;
        const int swz = (((half << 2) + quad) ^ (row & 7)) << 3;
        bt[c] = *(const short8*)&sm.st.B[row][swz];
      }
#pragma unroll
      for (int c = 0; c < 3; ++c)
#pragma unroll
        for (int mt = 0; mt < 8; ++mt)
          acc[c][mt] = __builtin_amdgcn_mfma_f32_16x16x32_bf16(af[mt], bt[c], acc[c][mt], 0, 0, 0);
    }
  }
  __syncthreads();  // staging buffers dead; safe to overwrite via union

  // acc -> qkv LDS (bf16). D row = mt*16 + quad*4 + r -> site mt, f = quad*4+r
#pragma unroll
  for (int c = 0; c < 3; ++c)
#pragma unroll
    for (int mt = 0; mt < 8; ++mt)
#pragma unroll
      for (int r = 0; r < 4; ++r)
        sm.at.qkv[mt][quad * 4 + r][c * 64 + w * 16 + c15] = f2bf(acc[c][mt][r]);
  __syncthreads();

  // ---- attention: wave w handles sites 2w, 2w+1 --------------------------
  const int i_ = lane >> 2, j4 = lane & 3, dg = lane & 3;
  for (int sblk = 0; sblk < 2; ++sblk) {
    const int s = w * 2 + sblk;
    float s0 = 0.f, s1 = 0.f, s2 = 0.f, s3 = 0.f;
#pragma unroll
    for (int d8 = 0; d8 < 8; ++d8) {
      const short8 q8 = *(const short8*)&sm.at.qkv[s][i_][d8 * 8];
      const short8 k0 = *(const short8*)&sm.at.qkv[s][j4][64 + d8 * 8];
      const short8 k1 = *(const short8*)&sm.at.qkv[s][4 + j4][64 + d8 * 8];
      const short8 k2 = *(const short8*)&sm.at.qkv[s][8 + j4][64 + d8 * 8];
      const short8 k3 = *(const short8*)&sm.at.qkv[s][12 + j4][64 + d8 * 8];
#pragma unroll
      for (int e = 0; e < 8; ++e) {
        const float qe = bf2f((u16)q8[e]);
        s0 += qe * bf2f((u16)k0[e]);
        s1 += qe * bf2f((u16)k1[e]);
        s2 += qe * bf2f((u16)k2[e]);
        s3 += qe * bf2f((u16)k3[e]);
      }
    }
    const float* pb = pos_bias + hd * 256 + i_ * 16;
    s0 += pb[j4]; s1 += pb[4 + j4]; s2 += pb[8 + j4]; s3 += pb[12 + j4];
    float mx = fmaxf(fmaxf(s0, s1), fmaxf(s2, s3));
    mx = fmaxf(mx, __shfl_xor(mx, 1));
    mx = fmaxf(mx, __shfl_xor(mx, 2));
    const float e0 = __expf(s0 - mx), e1 = __expf(s1 - mx);
    const float e2 = __expf(s2 - mx), e3 = __expf(s3 - mx);
    float sum = e0 + e1 + e2 + e3;
    sum += __shfl_xor(sum, 1);
    sum += __shfl_xor(sum, 2);
    const float inv = 1.0f / sum;
    sm.at.p[s][i_][j4] = e0 * inv;
    sm.at.p[s][i_][4 + j4] = e1 * inv;
    sm.at.p[s][i_][8 + j4] = e2 * inv;
    sm.at.p[s][i_][12 + j4] = e3 * inv;
    __syncthreads();

    // out = P @ V. lane: row i_, d-range dg*16..+16
    float o[16];
#pragma unroll
    for (int e = 0; e < 16; ++e) o[e] = 0.f;
#pragma unroll 4
    for (int j = 0; j < 16; ++j) {
      const float pij = sm.at.p[s][i_][j];
      const short8 v0 = *(const short8*)&sm.at.qkv[s][j][128 + dg * 16];
      const short8 v1 = *(const short8*)&sm.at.qkv[s][j][128 + dg * 16 + 8];
#pragma unroll
      for (int e = 0; e < 8; ++e) {
        o[e] += pij * bf2f((u16)v0[e]);
        o[8 + e] += pij * bf2f((u16)v1[e]);
      }
    }
    union { u16 us[16]; uint4 q[2]; } pk;
#pragma unroll
    for (int e = 0; e < 16; ++e) pk.us[e] = f2bf(o[e]);
    const int s_g = (m0 >> 4) + s;
    const int b = s_g >> 10, sp = s_g & 1023;
    uint4* dst = (uint4*)(AO + ((size_t)(b * 16384 + i_ * 1024 + sp)) * 512 +
                          hd * 64 + dg * 16);
    dst[0] = pk.q[0];
    dst[1] = pk.q[1];
  }
}

// ---------------- out projection GEMM + transposed store ------------------
struct K2St { u16 A[128][64]; u16 B[128][64]; };
union K2Sm { K2St st; float C[64][130]; };

__global__ __launch_bounds__(256) void k_proj(const u16* __restrict__ AO,
                                              const u16* __restrict__ WO,
                                              float* __restrict__ out) {
  const int tid = threadIdx.x, w = tid >> 6, lane = tid & 63;
  const int c15 = lane & 15, quad = lane >> 4;
  const int bid = blockIdx.x;          // 1024 blocks
  const int nb = bid & 3, mb = bid >> 2;
  const int m0 = mb << 7, n0 = nb << 7;
  const int b = m0 >> 14, mloc = m0 & 16383;
  __shared__ K2Sm sm;
  f32x4 acc[8][2];
#pragma unroll
  for (int mt = 0; mt < 8; ++mt) {
    acc[mt][0] = f32x4{0.f, 0.f, 0.f, 0.f};
    acc[mt][1] = f32x4{0.f, 0.f, 0.f, 0.f};
  }
  const int lr = lane >> 3, lcb = lane & 7;
  for (int kk = 0; kk < 8; ++kk) {
    __syncthreads();
    const int kc = kk << 6;
#pragma unroll
    for (int t2 = 0; t2 < 4; ++t2) {
      const int r = w * 32 + t2 * 8 + lr;
      const int swcol = kc + ((lcb ^ (r & 7)) << 3);
      async16(AO + (size_t)(m0 + r) * 512 + swcol, &sm.st.A[w * 32 + t2 * 8][0]);
      async16(WO + (size_t)(n0 + r) * 512 + swcol, &sm.st.B[w * 32 + t2 * 8][0]);
    }
    __syncthreads();
#pragma unroll
    for (int half = 0; half < 2; ++half) {
      short8 af[8], bt[2];
#pragma unroll
      for (int mt = 0; mt < 8; ++mt) {
        const int row = mt * 16 + c15;
        const int swz = (((half << 2) + quad) ^ (row & 7)) << 3;
        af[mt] = *(const short8*)&sm.st.A[row][swz];
      }
#pragma unroll
      for (int nt = 0; nt < 2; ++nt) {
        const int row = w * 32 + nt * 16 + c15;
        const int swz = (((half << 2) + quad) ^ (row & 7)) << 3;
        bt[nt] = *(const short8*)&sm.st.B[row][swz];
      }
#pragma unroll
      for (int mt = 0; mt < 8; ++mt) {
        acc[mt][0] = __builtin_amdgcn_mfma_f32_16x16x32_bf16(af[mt], bt[0], acc[mt][0], 0, 0, 0);
        acc[mt][1] = __builtin_amdgcn_mfma_f32_16x16x32_bf16(af[mt], bt[1], acc[mt][1], 0, 0, 0);
      }
    }
  }
  __syncthreads();
#pragma unroll
  for (int h = 0; h < 2; ++h) {
#pragma unroll
    for (int mt2 = 0; mt2 < 4; ++mt2) {
      const int mt = h * 4 + mt2;
#pragma unroll
      for (int nt = 0; nt < 2; ++nt)
#pragma unroll
        for (int r = 0; r < 4; ++r)
          sm.C[mt2 * 16 + quad * 4 + r][w * 32 + nt * 16 + c15] = acc[mt][nt][r];
    }
    __syncthreads();
    for (int jj = 0; jj < 32; ++jj) {
      const int ch = n0 + w * 32 + jj;
      out[(size_t)(b * 512 + ch) * 16384 + mloc + h * 64 + lane] = sm.C[lane][w * 32 + jj];
    }
    __syncthreads();
  }
}

extern "C" void kernel_launch(void* const* d_in, const int* in_sizes, int n_in,
                              void* d_out, int out_size, void* d_ws, size_t ws_size,
                              hipStream_t stream) {
  const float* x = (const float*)d_in[0];
  const float* pos_bias = (const float*)d_in[1];
  const float* w_qkv = (const float*)d_in[2];
  const float* w_out = (const float*)d_in[3];
  float* out = (float*)d_out;
  char* ws = (char*)d_ws;
  // ws layout (bytes): XT 33554432 | AO 33554432 | WQ 1572864 | WO 524288
  u16* XT = (u16*)(ws);
  u16* AO = (u16*)(ws + (size_t)33554432);
  u16* WQ = (u16*)(ws + (size_t)67108864);
  u16* WO = (u16*)(ws + (size_t)68681728);

  hipLaunchKernelGGL(k_wt, dim3(768), dim3(256), 0, stream, w_qkv, WQ, 512, 1536, 512);
  hipLaunchKernelGGL(k_wt, dim3(256), dim3(256), 0, stream, w_out, WO, 512, 512, 0);
  hipLaunchKernelGGL(k_xt, dim3(16384), dim3(256), 0, stream, x, XT);
  hipLaunchKernelGGL(k_qkv_attn, dim3(2048), dim3(256), 0, stream, XT, WQ, pos_bias, AO);
  hipLaunchKernelGGL(k_proj, dim3(1024), dim3(256), 0, stream, AO, WO, out);
}

// Round 4
// 246.158 us; speedup vs baseline: 1.2442x; 1.2442x over previous
//
#include <hip/hip_runtime.h>

typedef unsigned short u16;
typedef unsigned int u32;
typedef __attribute__((ext_vector_type(8))) short short8;
typedef __attribute__((ext_vector_type(4))) float f32x4;

__device__ __forceinline__ u16 f2bf(float f) {
  u32 u = __builtin_bit_cast(u32, f);
  u += 0x7fffu + ((u >> 16) & 1u);
  return (u16)(u >> 16);
}

__device__ __forceinline__ void async16(const void* g, void* l) {
  __builtin_amdgcn_global_load_lds(
      (const __attribute__((address_space(1))) u32*)g,
      (__attribute__((address_space(3))) u32*)l, 16, 0, 0);
}

// ---------------- weight transpose: in (K x N) f32 -> outT (N x K) bf16 ----
// scaleN: rows n < scaleN get * 0.125 (folds q-scale into w_qkv)
// perm: if nonzero, permute k within each 64-block: p(k)=(k&15)*4+((k>>4)&3)
__global__ __launch_bounds__(256) void k_wt(const float* __restrict__ in,
                                            u16* __restrict__ outT,
                                            int K, int N, int scaleN, int perm) {
  const int bid = blockIdx.x;
  const int ntiles = N >> 5;
  const int nt = bid % ntiles, kt = bid / ntiles;
  const int n0 = nt << 5, k0 = kt << 5;
  __shared__ float tile[32][33];
  const int t = threadIdx.x;
#pragma unroll
  for (int i = 0; i < 4; ++i) {
    const int e = t + i * 256, r = e >> 5, c = e & 31;  // r: k, c: n
    tile[c][r] = in[(size_t)(k0 + r) * N + n0 + c];
  }
  __syncthreads();
#pragma unroll
  for (int i = 0; i < 4; ++i) {
    const int e = t + i * 256, r = e >> 5, c = e & 31;  // r: n, c: k
    float v = tile[r][c];
    if (n0 + r < scaleN) v *= 0.125f;
    const int kcol = k0 + c;
    const int kp = perm ? ((kcol & ~63) | ((kcol & 15) << 2) | ((kcol >> 4) & 3))
                        : kcol;
    outT[(size_t)(n0 + r) * K + kp] = f2bf(v);
  }
}

// ---- x transpose: (b,c,f,h,w) f32 -> XT[(b,spatial)*16+f][c] bf16 (site-major)
__global__ __launch_bounds__(256) void k_xt(const float* __restrict__ x,
                                            u16* __restrict__ XT) {
  const int bid = blockIdx.x;
  const int plane = bid & 31;   // b*16 + f
  const int rest = bid >> 5;
  const int mt = rest & 31, ct = rest >> 5;
  const int bb = plane >> 4, f = plane & 15;
  const int m0 = mt << 5, c0 = ct << 5;
  __shared__ float tile[32][33];
  const int t = threadIdx.x;
#pragma unroll
  for (int i = 0; i < 4; ++i) {
    const int e = t + i * 256, r = e >> 5, c = e & 31;  // r: ch, c: m(spatial)
    tile[c][r] = x[((size_t)((bb * 512 + c0 + r) * 16 + f)) * 1024 + m0 + c];
  }
  __syncthreads();
#pragma unroll
  for (int i = 0; i < 4; ++i) {
    const int e = t + i * 256, r = e >> 5, c = e & 31;  // r: m, c: ch
    XT[((size_t)((bb * 1024 + m0 + r) * 16 + f)) * 512 + c0 + c] = f2bf(tile[r][c]);
  }
}

// ---------------- fused QKV GEMM + MFMA attention -------------------------
// block = (128 rows = 8 sites x 16 f) x (one head: q|k|v 192 cols), K=512.
// Phase 1: async16-staged MFMA GEMM. Phase 2: acc -> LDS (q,k,vt bf16),
// S=Q.K^T via MFMA, shfl softmax in C-layout, P zero-padded to K=32 overlaid
// on dead q[s], PV via MFMA, pi-permuted coalesced store.
struct A3St { u16 A[128][64]; u16 B[192][64]; };                   // 40960 B
struct A3At { u16 q[8][16][64]; u16 k[8][16][64]; u16 vt[8][64][16]; u16 pad[16]; };
union A3Sm { A3St st; A3At at; };                                  // 49184 B

__global__ __launch_bounds__(256) void k_qkv_attn(const u16* __restrict__ XT,
                                                  const u16* __restrict__ WQ,
                                                  const float* __restrict__ pos_bias,
                                                  u16* __restrict__ AO) {
  const int tid = threadIdx.x;
  const int w = tid >> 6, lane = tid & 63;
  const int c15 = lane & 15, quad = lane >> 4;
  const int bid = blockIdx.x;          // 2048 blocks = 256 M-tiles x 8 heads
  const int hd = bid & 7, m0 = (bid >> 3) << 7;

  __shared__ A3Sm sm;

  const int lr = lane >> 3, lcb = lane & 7;

  f32x4 acc[3][8];
#pragma unroll
  for (int c = 0; c < 3; ++c)
#pragma unroll
    for (int mt = 0; mt < 8; ++mt) acc[c][mt] = f32x4{0.f, 0.f, 0.f, 0.f};

  for (int kk = 0; kk < 8; ++kk) {
    __syncthreads();
    const int kc = kk << 6;
    // A: 128 rows, wave w stages rows w*32..+32
#pragma unroll
    for (int t2 = 0; t2 < 4; ++t2) {
      const int r = w * 32 + t2 * 8 + lr;
      const int swcol = kc + ((lcb ^ (r & 7)) << 3);
      async16(XT + (size_t)(m0 + r) * 512 + swcol, &sm.st.A[w * 32 + t2 * 8][0]);
    }
    // B: 192 rows (q|k|v of head hd), wave w stages rows w*48..+48
#pragma unroll
    for (int t2 = 0; t2 < 6; ++t2) {
      const int j = w * 48 + t2 * 8 + lr;
      const int grow = (j >> 6) * 512 + hd * 64 + (j & 63);
      const int swcol = kc + ((lcb ^ (j & 7)) << 3);
      async16(WQ + (size_t)grow * 512 + swcol, &sm.st.B[w * 48 + t2 * 8][0]);
    }
    __syncthreads();
#pragma unroll
    for (int half = 0; half < 2; ++half) {
      short8 af[8], bt[3];
#pragma unroll
      for (int mt = 0; mt < 8; ++mt) {
        const int row = mt * 16 + c15;
        const int swz = (((half << 2) + quad) ^ (row & 7)) << 3;
        af[mt] = *(const short8*)&sm.st.A[row][swz];
      }
#pragma unroll
      for (int c = 0; c < 3; ++c) {
        const int row = c * 64 + w * 16 + c15;
        const int swz = (((half << 2) + quad) ^ (row & 7)) << 3;
        bt[c] = *(const short8*)&sm.st.B[row][swz];
      }
#pragma unroll
      for (int c = 0; c < 3; ++c)
#pragma unroll
        for (int mt = 0; mt < 8; ++mt)
          acc[c][mt] = __builtin_amdgcn_mfma_f32_16x16x32_bf16(af[mt], bt[c], acc[c][mt], 0, 0, 0);
    }
  }
  __syncthreads();  // staging buffers dead; safe to overwrite via union

  // ---- write phase: acc -> q,k (chunk-swizzled), vt (transposed) ---------
  const int dloc = w * 16 + c15;       // this wave's d-slice
  const int ch_b = dloc >> 3, dl = dloc & 7;
#pragma unroll
  for (int mt = 0; mt < 8; ++mt) {
#pragma unroll
    for (int r = 0; r < 4; ++r) {
      const int f = quad * 4 + r;
      const int sw = ((ch_b ^ (f & 7)) << 3) | dl;
      sm.at.q[mt][f][sw] = f2bf(acc[0][mt][r]);
      sm.at.k[mt][f][sw] = f2bf(acc[1][mt][r]);
      sm.at.vt[mt][dloc][f] = f2bf(acc[2][mt][r]);
    }
  }
  __syncthreads();

  float pb[4];
#pragma unroll
  for (int r = 0; r < 4; ++r)
    pb[r] = pos_bias[hd * 256 + (quad * 4 + r) * 16 + c15];

  // ---- attention: wave w owns sites 2w, 2w+1 (q/k/vt[s] wave-private now) -
  for (int sblk = 0; sblk < 2; ++sblk) {
    const int s = w * 2 + sblk;
    // S = Q @ K^T (one 16x16 tile, K=64 over 2 MFMA)
    f32x4 sacc = f32x4{0.f, 0.f, 0.f, 0.f};
#pragma unroll
    for (int h = 0; h < 2; ++h) {
      const int chunk = (((h << 2) + quad) ^ (c15 & 7)) << 3;
      const short8 aq = *(const short8*)&sm.at.q[s][c15][chunk];
      const short8 bk = *(const short8*)&sm.at.k[s][c15][chunk];
      sacc = __builtin_amdgcn_mfma_f32_16x16x32_bf16(aq, bk, sacc, 0, 0, 0);
    }
    // compiler fence: q[s] reads above must not sink below the P overlay
    asm volatile("" ::: "memory");
    // overlay P (u16[16][32], cols 16..31 zero) onto dead q[s]
    u16* lp = &sm.at.q[s][0][0];
#pragma unroll
    for (int e = 0; e < 4; ++e) lp[c15 * 32 + 16 + quad * 4 + e] = 0;
    // softmax rows i=quad*4+r across c15-lanes (bias added pre-max)
#pragma unroll
    for (int r = 0; r < 4; ++r) {
      float sv = sacc[r] + pb[r];
      float mx = sv;
      mx = fmaxf(mx, __shfl_xor(mx, 1));
      mx = fmaxf(mx, __shfl_xor(mx, 2));
      mx = fmaxf(mx, __shfl_xor(mx, 4));
      mx = fmaxf(mx, __shfl_xor(mx, 8));
      const float e = __expf(sv - mx);
      float sum = e;
      sum += __shfl_xor(sum, 1);
      sum += __shfl_xor(sum, 2);
      sum += __shfl_xor(sum, 4);
      sum += __shfl_xor(sum, 8);
      lp[(quad * 4 + r) * 32 + c15] = f2bf(e / sum);
    }
    // compiler fence: P writes above must complete before the ap read below
    asm volatile("" ::: "memory");
    // PV: A = P (K padded to 32, cols 16..31 exactly 0), B = V via vt rows=d.
    // For quad>=2 (k=16..31) A is zero, so clamp the vt read to a valid
    // in-row chunk ((quad&1)*8): contributes 0, never touches OOB/uninit LDS.
    const short8 ap = *(const short8*)&lp[c15 * 32 + quad * 8];
    f32x4 oacc[4];
#pragma unroll
    for (int t = 0; t < 4; ++t) {
      const short8 bv = *(const short8*)&sm.at.vt[s][t * 16 + c15][(quad & 1) * 8];
      oacc[t] = __builtin_amdgcn_mfma_f32_16x16x32_bf16(ap, bv, f32x4{0.f, 0.f, 0.f, 0.f}, 0, 0, 0);
    }
    // store: out[i=quad*4+r][d=t*16+c15] -> AO col hd*64 + pi(d), pi(d)=c15*4+t
    const int s_g = (m0 >> 4) + s;
    const int bb = s_g >> 10, sp = s_g & 1023;
#pragma unroll
    for (int r = 0; r < 4; ++r) {
      union { u16 us[4]; uint2 v; } pk;
#pragma unroll
      for (int t = 0; t < 4; ++t) pk.us[t] = f2bf(oacc[t][r]);
      *(uint2*)(AO + ((size_t)(bb * 16384 + (quad * 4 + r) * 1024 + sp)) * 512 +
                hd * 64 + c15 * 4) = pk.v;
    }
  }
}

// ---------------- out projection GEMM + transposed store ------------------
struct K2St { u16 A[128][64]; u16 B[128][64]; };
union K2Sm { K2St st; float C[64][130]; };

__global__ __launch_bounds__(256) void k_proj(const u16* __restrict__ AO,
                                              const u16* __restrict__ WO,
                                              float* __restrict__ out) {
  const int tid = threadIdx.x, w = tid >> 6, lane = tid & 63;
  const int c15 = lane & 15, quad = lane >> 4;
  const int bid = blockIdx.x;          // 1024 blocks
  const int nb = bid & 3, mb = bid >> 2;
  const int m0 = mb << 7, n0 = nb << 7;
  const int b = m0 >> 14, mloc = m0 & 16383;
  __shared__ K2Sm sm;
  f32x4 acc[8][2];
#pragma unroll
  for (int mt = 0; mt < 8; ++mt) {
    acc[mt][0] = f32x4{0.f, 0.f, 0.f, 0.f};
    acc[mt][1] = f32x4{0.f, 0.f, 0.f, 0.f};
  }
  const int lr = lane >> 3, lcb = lane & 7;
  for (int kk = 0; kk < 8; ++kk) {
    __syncthreads();
    const int kc = kk << 6;
#pragma unroll
    for (int t2 = 0; t2 < 4; ++t2) {
      const int r = w * 32 + t2 * 8 + lr;
      const int swcol = kc + ((lcb ^ (r & 7)) << 3);
      async16(AO + (size_t)(m0 + r) * 512 + swcol, &sm.st.A[w * 32 + t2 * 8][0]);
      async16(WO + (size_t)(n0 + r) * 512 + swcol, &sm.st.B[w * 32 + t2 * 8][0]);
    }
    __syncthreads();
#pragma unroll
    for (int half = 0; half < 2; ++half) {
      short8 af[8], bt[2];
#pragma unroll
      for (int mt = 0; mt < 8; ++mt) {
        const int row = mt * 16 + c15;
        const int swz = (((half << 2) + quad) ^ (row & 7)) << 3;
        af[mt] = *(const short8*)&sm.st.A[row][swz];
      }
#pragma unroll
      for (int nt = 0; nt < 2; ++nt) {
        const int row = w * 32 + nt * 16 + c15;
        const int swz = (((half << 2) + quad) ^ (row & 7)) << 3;
        bt[nt] = *(const short8*)&sm.st.B[row][swz];
      }
#pragma unroll
      for (int mt = 0; mt < 8; ++mt) {
        acc[mt][0] = __builtin_amdgcn_mfma_f32_16x16x32_bf16(af[mt], bt[0], acc[mt][0], 0, 0, 0);
        acc[mt][1] = __builtin_amdgcn_mfma_f32_16x16x32_bf16(af[mt], bt[1], acc[mt][1], 0, 0, 0);
      }
    }
  }
  __syncthreads();
#pragma unroll
  for (int h = 0; h < 2; ++h) {
#pragma unroll
    for (int mt2 = 0; mt2 < 4; ++mt2) {
      const int mt = h * 4 + mt2;
#pragma unroll
      for (int nt = 0; nt < 2; ++nt)
#pragma unroll
        for (int r = 0; r < 4; ++r)
          sm.C[mt2 * 16 + quad * 4 + r][w * 32 + nt * 16 + c15] = acc[mt][nt][r];
    }
    __syncthreads();
    for (int jj = 0; jj < 32; ++jj) {
      const int ch = n0 + w * 32 + jj;
      out[(size_t)(b * 512 + ch) * 16384 + mloc + h * 64 + lane] = sm.C[lane][w * 32 + jj];
    }
    __syncthreads();
  }
}

extern "C" void kernel_launch(void* const* d_in, const int* in_sizes, int n_in,
                              void* d_out, int out_size, void* d_ws, size_t ws_size,
                              hipStream_t stream) {
  const float* x = (const float*)d_in[0];
  const float* pos_bias = (const float*)d_in[1];
  const float* w_qkv = (const float*)d_in[2];
  const float* w_out = (const float*)d_in[3];
  float* out = (float*)d_out;
  char* ws = (char*)d_ws;
  // ws layout (bytes): XT 33554432 | AO 33554432 | WQ 1572864 | WO 524288
  u16* XT = (u16*)(ws);
  u16* AO = (u16*)(ws + (size_t)33554432);
  u16* WQ = (u16*)(ws + (size_t)67108864);
  u16* WO = (u16*)(ws + (size_t)68681728);

  hipLaunchKernelGGL(k_wt, dim3(768), dim3(256), 0, stream, w_qkv, WQ, 512, 1536, 512, 0);
  hipLaunchKernelGGL(k_wt, dim3(256), dim3(256), 0, stream, w_out, WO, 512, 512, 0, 1);
  hipLaunchKernelGGL(k_xt, dim3(16384), dim3(256), 0, stream, x, XT);
  hipLaunchKernelGGL(k_qkv_attn, dim3(2048), dim3(256), 0, stream, XT, WQ, pos_bias, AO);
  hipLaunchKernelGGL(k_proj, dim3(1024), dim3(256), 0, stream, AO, WO, out);
}

// Round 6
// 240.813 us; speedup vs baseline: 1.2718x; 1.0222x over previous
//
#include <hip/hip_runtime.h>

typedef unsigned short u16;
typedef unsigned int u32;
typedef unsigned long long u64;
typedef __attribute__((ext_vector_type(8))) short short8;
typedef __attribute__((ext_vector_type(4))) float f32x4;

__device__ __forceinline__ u16 f2bf(float f) {
  u32 u = __builtin_bit_cast(u32, f);
  u += 0x7fffu + ((u >> 16) & 1u);
  return (u16)(u >> 16);
}
__device__ __forceinline__ u32 pk2bf(float a, float b) {
  return (u32)f2bf(a) | ((u32)f2bf(b) << 16);
}

__device__ __forceinline__ void async16(const void* g, void* l) {
  __builtin_amdgcn_global_load_lds(
      (const __attribute__((address_space(1))) u32*)g,
      (__attribute__((address_space(3))) u32*)l, 16, 0, 0);
}

// ---------------- weight transpose: in (K x N) f32 -> outT (N x K) bf16 ----
// scaleN: rows n < scaleN get * 0.125 (folds q-scale into w_qkv)
// perm: if nonzero, permute k within each 64-block: p(k)=(k&15)*4+((k>>4)&3)
__global__ __launch_bounds__(256) void k_wt(const float* __restrict__ in,
                                            u16* __restrict__ outT,
                                            int K, int N, int scaleN, int perm) {
  const int bid = blockIdx.x;
  const int ntiles = N >> 5;
  const int nt = bid % ntiles, kt = bid / ntiles;
  const int n0 = nt << 5, k0 = kt << 5;
  __shared__ float tile[32][33];
  const int t = threadIdx.x;
#pragma unroll
  for (int i = 0; i < 4; ++i) {
    const int e = t + i * 256, r = e >> 5, c = e & 31;  // r: k, c: n
    tile[c][r] = in[(size_t)(k0 + r) * N + n0 + c];
  }
  __syncthreads();
#pragma unroll
  for (int i = 0; i < 4; ++i) {
    const int e = t + i * 256, r = e >> 5, c = e & 31;  // r: n, c: k
    float v = tile[r][c];
    if (n0 + r < scaleN) v *= 0.125f;
    const int kcol = k0 + c;
    const int kp = perm ? ((kcol & ~63) | ((kcol & 15) << 2) | ((kcol >> 4) & 3))
                        : kcol;
    outT[(size_t)(n0 + r) * K + kp] = f2bf(v);
  }
}

// ---- x transpose: (b,c,f,h,w) f32 -> XT[(b,spatial)*16+f][c] bf16 ---------
// float4 loads (16 B/lane), u64 stores (8 B/lane), LDS 32x36 f32 tile.
__global__ __launch_bounds__(256) void k_xt(const float* __restrict__ x,
                                            u16* __restrict__ XT) {
  const int bid = blockIdx.x;          // 16384 = 32 planes x 32 mt x 16 ct
  const int plane = bid & 31;          // b*16 + f
  const int rest = bid >> 5;
  const int mt = rest & 31, ct = rest >> 5;
  const int bb = plane >> 4, f = plane & 15;
  const int m0 = mt << 5, c0 = ct << 5;
  __shared__ float tile[32][36];
  const int t = threadIdx.x;
  const int lr = t >> 3, lc = t & 7;   // load: c-row, float4 chunk of m
  const float4 v4 = *(const float4*)
      &x[((size_t)((bb * 512 + c0 + lr) * 16 + f)) * 1024 + m0 + lc * 4];
  *(float4*)&tile[lr][lc * 4] = v4;
  __syncthreads();
  const int m = t >> 3, cc = t & 7;    // store: m-row, c-chunk of 4
  union { u32 uu[2]; u64 q; } pk;
  pk.uu[0] = pk2bf(tile[cc * 4 + 0][m], tile[cc * 4 + 1][m]);
  pk.uu[1] = pk2bf(tile[cc * 4 + 2][m], tile[cc * 4 + 3][m]);
  *(u64*)&XT[((size_t)((bb * 1024 + m0 + m) * 16 + f)) * 512 + c0 + cc * 4] = pk.q;
}

// ---------------- fused QKV GEMM + MFMA attention -------------------------
// block = (128 rows = 8 sites x 16 f) x (one head: q|k|v 192 cols), K=512.
// bid = head*256 + mtile so the 8 head-blocks of one A-tile share an XCD.
// K-loop fully unrolled; staging pointers hoisted (imm offsets in-loop).
struct A3St { u16 A[128][64]; u16 B[192][64]; };                   // 40960 B
struct A3At { u16 q[8][16][64]; u16 k[8][16][64]; u16 vt[8][64][16]; u16 pad[16]; };
union A3Sm { A3St st; A3At at; };                                  // 49184 B

__global__ __launch_bounds__(256) void k_qkv_attn(const u16* __restrict__ XT,
                                                  const u16* __restrict__ WQ,
                                                  const float* __restrict__ pos_bias,
                                                  u16* __restrict__ AO) {
  const int tid = threadIdx.x;
  const int w = tid >> 6, lane = tid & 63;
  const int c15 = lane & 15, quad = lane >> 4;
  const int bid = blockIdx.x;          // 2048 = 8 heads x 256 M-tiles
  const int hd = bid >> 8, m0 = (bid & 255) << 7;

  __shared__ A3Sm sm;

  const int lr = lane >> 3, lcb = lane & 7;

  // hoisted staging pointers (kk advances via constant byte offsets)
  const u16* aptr[4];
  const u16* bptr[6];
#pragma unroll
  for (int t2 = 0; t2 < 4; ++t2) {
    const int r = w * 32 + t2 * 8 + lr;
    aptr[t2] = XT + (size_t)(m0 + r) * 512 + ((lcb ^ (r & 7)) << 3);
  }
#pragma unroll
  for (int t2 = 0; t2 < 6; ++t2) {
    const int j = w * 48 + t2 * 8 + lr;
    const int grow = (j >> 6) * 512 + hd * 64 + (j & 63);
    bptr[t2] = WQ + (size_t)grow * 512 + ((lcb ^ (j & 7)) << 3);
  }

  f32x4 acc[3][8];
#pragma unroll
  for (int c = 0; c < 3; ++c)
#pragma unroll
    for (int mt = 0; mt < 8; ++mt) acc[c][mt] = f32x4{0.f, 0.f, 0.f, 0.f};

#pragma unroll
  for (int kk = 0; kk < 8; ++kk) {
    __syncthreads();
#pragma unroll
    for (int t2 = 0; t2 < 4; ++t2)
      async16(aptr[t2] + (kk << 6), &sm.st.A[w * 32 + t2 * 8][0]);
#pragma unroll
    for (int t2 = 0; t2 < 6; ++t2)
      async16(bptr[t2] + (kk << 6), &sm.st.B[w * 48 + t2 * 8][0]);
    __syncthreads();
#pragma unroll
    for (int half = 0; half < 2; ++half) {
      short8 af[8], bt[3];
#pragma unroll
      for (int mt = 0; mt < 8; ++mt) {
        const int row = mt * 16 + c15;
        const int swz = (((half << 2) + quad) ^ (row & 7)) << 3;
        af[mt] = *(const short8*)&sm.st.A[row][swz];
      }
#pragma unroll
      for (int c = 0; c < 3; ++c) {
        const int row = c * 64 + w * 16 + c15;
        const int swz = (((half << 2) + quad) ^ (row & 7)) << 3;
        bt[c] = *(const short8*)&sm.st.B[row][swz];
      }
#pragma unroll
      for (int c = 0; c < 3; ++c)
#pragma unroll
        for (int mt = 0; mt < 8; ++mt)
          acc[c][mt] = __builtin_amdgcn_mfma_f32_16x16x32_bf16(af[mt], bt[c], acc[c][mt], 0, 0, 0);
    }
  }
  __syncthreads();  // staging buffers dead; safe to overwrite via union

  // ---- write phase: acc -> q,k (chunk-swizzled scatter), vt (b64) --------
  const int dloc = w * 16 + c15;       // this wave's d-slice
  const int ch_b = dloc >> 3, dl = dloc & 7;
#pragma unroll
  for (int mt = 0; mt < 8; ++mt) {
#pragma unroll
    for (int r = 0; r < 4; ++r) {
      const int f = quad * 4 + r;
      const int sw = ((ch_b ^ (f & 7)) << 3) | dl;
      sm.at.q[mt][f][sw] = f2bf(acc[0][mt][r]);
      sm.at.k[mt][f][sw] = f2bf(acc[1][mt][r]);
    }
    union { u32 uu[2]; u64 q; } pv;
    pv.uu[0] = pk2bf(acc[2][mt][0], acc[2][mt][1]);
    pv.uu[1] = pk2bf(acc[2][mt][2], acc[2][mt][3]);
    *(u64*)&sm.at.vt[mt][dloc][quad * 4] = pv.q;
  }
  __syncthreads();

  float pb[4];
#pragma unroll
  for (int r = 0; r < 4; ++r)
    pb[r] = pos_bias[hd * 256 + (quad * 4 + r) * 16 + c15];

  // ---- attention: wave w owns sites 2w, 2w+1 (q/k/vt[s] wave-private now) -
  for (int sblk = 0; sblk < 2; ++sblk) {
    const int s = w * 2 + sblk;
    // S = Q @ K^T (one 16x16 tile, K=64 over 2 MFMA)
    f32x4 sacc = f32x4{0.f, 0.f, 0.f, 0.f};
#pragma unroll
    for (int h = 0; h < 2; ++h) {
      const int chunk = (((h << 2) + quad) ^ (c15 & 7)) << 3;
      const short8 aq = *(const short8*)&sm.at.q[s][c15][chunk];
      const short8 bk = *(const short8*)&sm.at.k[s][c15][chunk];
      sacc = __builtin_amdgcn_mfma_f32_16x16x32_bf16(aq, bk, sacc, 0, 0, 0);
    }
    // compiler fence: q[s] reads above must not sink below the P overlay
    asm volatile("" ::: "memory");
    // overlay P (u16[16][32], cols 16..31 zero) onto dead q[s]
    u16* lp = &sm.at.q[s][0][0];
#pragma unroll
    for (int e = 0; e < 4; ++e) lp[c15 * 32 + 16 + quad * 4 + e] = 0;
    // softmax rows i=quad*4+r across c15-lanes (bias added pre-max)
#pragma unroll
    for (int r = 0; r < 4; ++r) {
      float sv = sacc[r] + pb[r];
      float mx = sv;
      mx = fmaxf(mx, __shfl_xor(mx, 1));
      mx = fmaxf(mx, __shfl_xor(mx, 2));
      mx = fmaxf(mx, __shfl_xor(mx, 4));
      mx = fmaxf(mx, __shfl_xor(mx, 8));
      const float e = __expf(sv - mx);
      float sum = e;
      sum += __shfl_xor(sum, 1);
      sum += __shfl_xor(sum, 2);
      sum += __shfl_xor(sum, 4);
      sum += __shfl_xor(sum, 8);
      lp[(quad * 4 + r) * 32 + c15] = f2bf(e / sum);
    }
    // compiler fence: P writes above must complete before the ap read below
    asm volatile("" ::: "memory");
    // PV: A = P (K padded to 32, cols 16..31 exactly 0), B = V via vt rows=d.
    // For quad>=2 (k=16..31) A is zero, so clamp the vt read to a valid
    // in-row chunk ((quad&1)*8): contributes 0, never touches OOB/uninit LDS.
    const short8 ap = *(const short8*)&lp[c15 * 32 + quad * 8];
    f32x4 oacc[4];
#pragma unroll
    for (int t = 0; t < 4; ++t) {
      const short8 bv = *(const short8*)&sm.at.vt[s][t * 16 + c15][(quad & 1) * 8];
      oacc[t] = __builtin_amdgcn_mfma_f32_16x16x32_bf16(ap, bv, f32x4{0.f, 0.f, 0.f, 0.f}, 0, 0, 0);
    }
    // store: out[i=quad*4+r][d=t*16+c15] -> AO col hd*64 + pi(d), pi(d)=c15*4+t
    const int s_g = (m0 >> 4) + s;
    const int bb = s_g >> 10, sp = s_g & 1023;
#pragma unroll
    for (int r = 0; r < 4; ++r) {
      union { u32 uu[2]; uint2 v; } pk;
      pk.uu[0] = pk2bf(oacc[0][r], oacc[1][r]);
      pk.uu[1] = pk2bf(oacc[2][r], oacc[3][r]);
      *(uint2*)(AO + ((size_t)(bb * 16384 + (quad * 4 + r) * 1024 + sp)) * 512 +
                hd * 64 + c15 * 4) = pk.v;
    }
  }
}

// ---------------- out projection GEMM + transposed store ------------------
struct K2St { u16 A[128][64]; u16 B[128][64]; };
union K2Sm { K2St st; float C[64][130]; };

__global__ __launch_bounds__(256) void k_proj(const u16* __restrict__ AO,
                                              const u16* __restrict__ WO,
                                              float* __restrict__ out) {
  const int tid = threadIdx.x, w = tid >> 6, lane = tid & 63;
  const int c15 = lane & 15, quad = lane >> 4;
  const int bid = blockIdx.x;          // 1024 = 4 n-tiles x 256 m-tiles
  const int mb = bid & 255, nb = bid >> 8;  // A-tile reusers share an XCD
  const int m0 = mb << 7, n0 = nb << 7;
  const int b = m0 >> 14, mloc = m0 & 16383;
  __shared__ K2Sm sm;
  f32x4 acc[8][2];
#pragma unroll
  for (int mt = 0; mt < 8; ++mt) {
    acc[mt][0] = f32x4{0.f, 0.f, 0.f, 0.f};
    acc[mt][1] = f32x4{0.f, 0.f, 0.f, 0.f};
  }
  const int lr = lane >> 3, lcb = lane & 7;
  const u16* aptr[4];
  const u16* bptr[4];
#pragma unroll
  for (int t2 = 0; t2 < 4; ++t2) {
    const int r = w * 32 + t2 * 8 + lr;
    const int sw = (lcb ^ (r & 7)) << 3;
    aptr[t2] = AO + (size_t)(m0 + r) * 512 + sw;
    bptr[t2] = WO + (size_t)(n0 + r) * 512 + sw;
  }
#pragma unroll
  for (int kk = 0; kk < 8; ++kk) {
    __syncthreads();
#pragma unroll
    for (int t2 = 0; t2 < 4; ++t2) {
      async16(aptr[t2] + (kk << 6), &sm.st.A[w * 32 + t2 * 8][0]);
      async16(bptr[t2] + (kk << 6), &sm.st.B[w * 32 + t2 * 8][0]);
    }
    __syncthreads();
#pragma unroll
    for (int half = 0; half < 2; ++half) {
      short8 af[8], bt[2];
#pragma unroll
      for (int mt = 0; mt < 8; ++mt) {
        const int row = mt * 16 + c15;
        const int swz = (((half << 2) + quad) ^ (row & 7)) << 3;
        af[mt] = *(const short8*)&sm.st.A[row][swz];
      }
#pragma unroll
      for (int nt = 0; nt < 2; ++nt) {
        const int row = w * 32 + nt * 16 + c15;
        const int swz = (((half << 2) + quad) ^ (row & 7)) << 3;
        bt[nt] = *(const short8*)&sm.st.B[row][swz];
      }
#pragma unroll
      for (int mt = 0; mt < 8; ++mt) {
        acc[mt][0] = __builtin_amdgcn_mfma_f32_16x16x32_bf16(af[mt], bt[0], acc[mt][0], 0, 0, 0);
        acc[mt][1] = __builtin_amdgcn_mfma_f32_16x16x32_bf16(af[mt], bt[1], acc[mt][1], 0, 0, 0);
      }
    }
  }
  __syncthreads();
#pragma unroll
  for (int h = 0; h < 2; ++h) {
#pragma unroll
    for (int mt2 = 0; mt2 < 4; ++mt2) {
      const int mt = h * 4 + mt2;
#pragma unroll
      for (int nt = 0; nt < 2; ++nt)
#pragma unroll
        for (int r = 0; r < 4; ++r)
          sm.C[mt2 * 16 + quad * 4 + r][w * 32 + nt * 16 + c15] = acc[mt][nt][r];
    }
    __syncthreads();
    for (int jj = 0; jj < 32; ++jj) {
      const int ch = n0 + w * 32 + jj;
      out[(size_t)(b * 512 + ch) * 16384 + mloc + h * 64 + lane] = sm.C[lane][w * 32 + jj];
    }
    __syncthreads();
  }
}

extern "C" void kernel_launch(void* const* d_in, const int* in_sizes, int n_in,
                              void* d_out, int out_size, void* d_ws, size_t ws_size,
                              hipStream_t stream) {
  const float* x = (const float*)d_in[0];
  const float* pos_bias = (const float*)d_in[1];
  const float* w_qkv = (const float*)d_in[2];
  const float* w_out = (const float*)d_in[3];
  float* out = (float*)d_out;
  char* ws = (char*)d_ws;
  // ws layout (bytes): XT 33554432 | AO 33554432 | WQ 1572864 | WO 524288
  u16* XT = (u16*)(ws);
  u16* AO = (u16*)(ws + (size_t)33554432);
  u16* WQ = (u16*)(ws + (size_t)67108864);
  u16* WO = (u16*)(ws + (size_t)68681728);

  hipLaunchKernelGGL(k_wt, dim3(768), dim3(256), 0, stream, w_qkv, WQ, 512, 1536, 512, 0);
  hipLaunchKernelGGL(k_wt, dim3(256), dim3(256), 0, stream, w_out, WO, 512, 512, 0, 1);
  hipLaunchKernelGGL(k_xt, dim3(16384), dim3(256), 0, stream, x, XT);
  hipLaunchKernelGGL(k_qkv_attn, dim3(2048), dim3(256), 0, stream, XT, WQ, pos_bias, AO);
  hipLaunchKernelGGL(k_proj, dim3(1024), dim3(256), 0, stream, AO, WO, out);
}